// Round 2
// baseline (127.060 us; speedup 1.0000x reference)
//
#include <hip/hip_runtime.h>

// Problem constants (from setup_inputs): B=16, NEG=128, S=128, D=512, N_PRED=12
#define DIM 512
#define M_ROWS 2048      // B*S
#define BM 64
#define BN 64
#define BK 16

// ---------------- Kernel 1: c_proj = c @ W[k]^T + b[k] ----------------
// M=2048, N=512, K=512. A[m,k]=c, B[o,k]=W[k_sel][o][k] (both row-contig in k).
__global__ __launch_bounds__(256) void cproj_kernel(
    const float* __restrict__ c, const float* __restrict__ W,
    const float* __restrict__ bias, const int* __restrict__ kptr,
    float* __restrict__ cp) {
    const int ksel = kptr[0];
    const float* __restrict__ Wk = W + (size_t)ksel * DIM * DIM;
    const float* __restrict__ bk = bias + (size_t)ksel * DIM;

    __shared__ float As[BK][BM];
    __shared__ float Bs[BK][BN];

    const int bm = blockIdx.x % (M_ROWS / BM);   // 0..31
    const int bn = blockIdx.x / (M_ROWS / BM);   // 0..7
    const int t  = threadIdx.x;

    // staging: 64 rows x 16 k each tile; 256 threads load float4 each
    const int lrow = t >> 2;          // 0..63
    const int lk4  = (t & 3) * 4;     // 0,4,8,12
    // compute mapping: 16x16 threads, each 4x4 outputs
    const int tm = (t & 15) * 4;
    const int tn = (t >> 4) * 4;

    float acc[4][4] = {};

    const float* Arow = c  + (size_t)(bm * BM + lrow) * DIM + lk4;
    const float* Brow = Wk + (size_t)(bn * BN + lrow) * DIM + lk4;

    for (int k0 = 0; k0 < DIM; k0 += BK) {
        const float4 a4 = *(const float4*)(Arow + k0);
        const float4 b4 = *(const float4*)(Brow + k0);
        __syncthreads();   // previous iteration's LDS reads complete
        As[lk4 + 0][lrow] = a4.x; As[lk4 + 1][lrow] = a4.y;
        As[lk4 + 2][lrow] = a4.z; As[lk4 + 3][lrow] = a4.w;
        Bs[lk4 + 0][lrow] = b4.x; Bs[lk4 + 1][lrow] = b4.y;
        Bs[lk4 + 2][lrow] = b4.z; Bs[lk4 + 3][lrow] = b4.w;
        __syncthreads();
#pragma unroll
        for (int kk = 0; kk < BK; ++kk) {
            const float4 av = *(const float4*)&As[kk][tm];
            const float4 bv = *(const float4*)&Bs[kk][tn];
            const float a[4] = {av.x, av.y, av.z, av.w};
            const float b[4] = {bv.x, bv.y, bv.z, bv.w};
#pragma unroll
            for (int i = 0; i < 4; ++i)
#pragma unroll
                for (int j = 0; j < 4; ++j)
                    acc[i][j] = fmaf(a[i], b[j], acc[i][j]);
        }
    }

    const float4 bb = *(const float4*)(bk + bn * BN + tn);
    const float badd[4] = {bb.x, bb.y, bb.z, bb.w};
#pragma unroll
    for (int i = 0; i < 4; ++i) {
        float4 r;
        r.x = acc[i][0] + badd[0];
        r.y = acc[i][1] + badd[1];
        r.z = acc[i][2] + badd[2];
        r.w = acc[i][3] + badd[3];
        *(float4*)(cp + (size_t)(bm * BM + tm + i) * DIM + bn * BN + tn) = r;
    }
}

// ---------------- Kernel 2: out[b,n,s] = (1/512) * dot(cp[b,s,:], z[b,n,s,:]) ----
// One wave (64 lanes) per output element; 4 waves/block share a cp row via L1.
__global__ __launch_bounds__(256) void dot_kernel(
    const float* __restrict__ z, const float* __restrict__ cp,
    float* __restrict__ out) {
    const int bs   = blockIdx.x >> 5;        // b*128 + s  (0..2047)
    const int nt   = blockIdx.x & 31;        // n-tile of 4
    const int wave = threadIdx.x >> 6;
    const int lane = threadIdx.x & 63;
    const int b = bs >> 7;
    const int s = bs & 127;
    const int n = nt * 4 + wave;

    const size_t out_idx = ((size_t)(b * 128 + n)) * 128 + s;
    const size_t zbase   = out_idx * DIM;
    const size_t cbase   = (size_t)bs * DIM;

    float acc = 0.f;
#pragma unroll
    for (int p = 0; p < 2; ++p) {
        const float4 z4 = *(const float4*)(z  + zbase + p * 256 + lane * 4);
        const float4 c4 = *(const float4*)(cp + cbase + p * 256 + lane * 4);
        acc = fmaf(z4.x, c4.x, acc);
        acc = fmaf(z4.y, c4.y, acc);
        acc = fmaf(z4.z, c4.z, acc);
        acc = fmaf(z4.w, c4.w, acc);
    }
#pragma unroll
    for (int off = 32; off; off >>= 1) acc += __shfl_xor(acc, off);
    if (lane == 0) out[out_idx] = acc * (1.0f / 512.0f);
}

extern "C" void kernel_launch(void* const* d_in, const int* in_sizes, int n_in,
                              void* d_out, int out_size, void* d_ws, size_t ws_size,
                              hipStream_t stream) {
    const float* c    = (const float*)d_in[0];
    const float* z    = (const float*)d_in[1];
    const float* W    = (const float*)d_in[2];
    const float* bias = (const float*)d_in[3];
    const int*   kptr = (const int*)d_in[4];
    float* out = (float*)d_out;
    float* cp  = (float*)d_ws;   // 2048*512*4 = 4 MB scratch for c_proj

    // Kernel 1: 32 M-tiles x 8 N-tiles = 256 blocks
    cproj_kernel<<<dim3(256), dim3(256), 0, stream>>>(c, W, bias, kptr, cp);
    // Kernel 2: 2048 (b,s) rows x 32 n-tiles = 65536 blocks, 4 waves each
    dot_kernel<<<dim3(65536), dim3(256), 0, stream>>>(z, cp, out);
}